// Round 1
// baseline (255.863 us; speedup 1.0000x reference)
//
#include <hip/hip_runtime.h>
#include <math.h>

#define NUM_CLASSES 10
#define BATCH 2048
#define DIM 128

#define BM 64
#define BN 64
#define BK 32
#define LDA 68   // padded leading dim for LDS tiles (17 banks*4, 16B-aligned rows)

__device__ __constant__ float kInvT = 1.0f / 0.07f;   // 1/TEMPERATURE
#define RATIO 1.0f  // TEMPERATURE / BASE_TEMPERATURE

// ---------------------------------------------------------------------------
// 1) Row-normalize: g[r] = preds[r] / ||preds[r]||.  One wave per row.
// ---------------------------------------------------------------------------
__global__ __launch_bounds__(256) void normalize_kernel(
    const float* __restrict__ preds, float* __restrict__ g)
{
    int row  = blockIdx.x * 4 + (threadIdx.x >> 6);   // 4 rows per 256-thr block
    int lane = threadIdx.x & 63;
    const float2* src = (const float2*)(preds + (size_t)row * DIM);
    float2 v = src[lane];
    float ss = v.x * v.x + v.y * v.y;
#pragma unroll
    for (int m = 32; m; m >>= 1) ss += __shfl_xor(ss, m, 64);
    float rn = 1.0f / sqrtf(ss);
    float2* dst = (float2*)(g + (size_t)row * DIM);
    dst[lane] = make_float2(v.x * rn, v.y * rn);
}

// ---------------------------------------------------------------------------
// 2) Fused Gram + epilogue. Block = 64x64 tile of one class's Gram matrix.
//    acc[i][j] = g_a . g_b (cosine).  Epilogue: per-row sum of exp(logit)
//    (diag excluded) and label-masked sum of logit; atomicAdd into per-row
//    accumulators.
// ---------------------------------------------------------------------------
__global__ __launch_bounds__(256) void gram_kernel(
    const float* __restrict__ g, const int* __restrict__ target,
    float* __restrict__ denom, float* __restrict__ s2)
{
    const int cls  = blockIdx.z;
    const int row0 = blockIdx.y * BM;
    const int col0 = blockIdx.x * BN;
    const float* gc = g + (size_t)cls * BATCH * DIM;

    __shared__ float As[BK][LDA];   // [k][row], padded
    __shared__ float Bs[BK][LDA];   // [k][col], padded

    const int t  = threadIdx.x;
    const int tx = t & 15;          // 16 cols of threads -> 4 cols each
    const int ty = t >> 4;          // 16 rows of threads -> 4 rows each

    float acc[4][4] = {};

    for (int kt = 0; kt < DIM; kt += BK) {
        // Stage 64x32 A-tile and B-tile, transposed into LDS.
        // 512 float4 per tile; thread handles q = t and q+256.
#pragma unroll
        for (int s = 0; s < 2; ++s) {
            int q  = t + s * 256;
            int r  = q >> 3;            // 0..63
            int kq = (q & 7) << 2;      // 0,4,...,28
            float4 va = *(const float4*)(gc + (size_t)(row0 + r) * DIM + kt + kq);
            float4 vb = *(const float4*)(gc + (size_t)(col0 + r) * DIM + kt + kq);
            As[kq + 0][r] = va.x; As[kq + 1][r] = va.y;
            As[kq + 2][r] = va.z; As[kq + 3][r] = va.w;
            Bs[kq + 0][r] = vb.x; Bs[kq + 1][r] = vb.y;
            Bs[kq + 2][r] = vb.z; Bs[kq + 3][r] = vb.w;
        }
        __syncthreads();

#pragma unroll
        for (int k = 0; k < BK; ++k) {
            float4 a4 = *(const float4*)&As[k][ty * 4];
            float4 b4 = *(const float4*)&Bs[k][tx * 4];
            float av[4] = {a4.x, a4.y, a4.z, a4.w};
            float bv[4] = {b4.x, b4.y, b4.z, b4.w};
#pragma unroll
            for (int i = 0; i < 4; ++i)
#pragma unroll
                for (int j = 0; j < 4; ++j)
                    acc[i][j] += av[i] * bv[j];
        }
        __syncthreads();
    }

    // ---- epilogue ----
    int a_idx[4], b_idx[4], la[4], lb[4];
#pragma unroll
    for (int i = 0; i < 4; ++i) {
        a_idx[i] = row0 + ty * 4 + i;
        b_idx[i] = col0 + tx * 4 + i;
        la[i] = (target[a_idx[i]] == cls);
        lb[i] = (target[b_idx[i]] == cls);
    }

#pragma unroll
    for (int i = 0; i < 4; ++i) {
        float den = 0.0f, sp = 0.0f;
#pragma unroll
        for (int j = 0; j < 4; ++j) {
            if (a_idx[i] != b_idx[j]) {
                float logit = acc[i][j] * kInvT;
                den += __expf(logit);
                if (la[i] == lb[j]) sp += logit;
            }
        }
        // reduce across the 16 tx-lanes (contiguous within the wave)
#pragma unroll
        for (int m = 1; m < 16; m <<= 1) {
            den += __shfl_xor(den, m, 64);
            sp  += __shfl_xor(sp,  m, 64);
        }
        if (tx == 0) {
            atomicAdd(&denom[cls * BATCH + a_idx[i]], den);
            atomicAdd(&s2   [cls * BATCH + a_idx[i]], sp);
        }
    }
}

// ---------------------------------------------------------------------------
// 3) Finalize: class histogram -> cnt per row; loss = mean over rows of
//    -(ratio)*(s2/cnt - log(denom)); out = sum_i exp(-lv_i)*loss_i + lv_i.
// ---------------------------------------------------------------------------
__global__ __launch_bounds__(256) void final_kernel(
    const float* __restrict__ denom, const float* __restrict__ s2,
    const int* __restrict__ target, const float* __restrict__ log_vars,
    float* __restrict__ out)
{
    __shared__ int counts[NUM_CLASSES];
    __shared__ float wsum[4];
    int t = threadIdx.x;
    if (t < NUM_CLASSES) counts[t] = 0;
    __syncthreads();
    for (int i = t; i < BATCH; i += 256) atomicAdd(&counts[target[i]], 1);
    __syncthreads();

    float partial = 0.0f;
    for (int idx = t; idx < NUM_CLASSES * BATCH; idx += 256) {
        int i = idx >> 11;            // class
        int a = idx & (BATCH - 1);    // row
        int cnt = (target[a] == i) ? (counts[i] - 1) : (BATCH - counts[i] - 1);
        float mlpp = s2[idx] / (float)cnt - logf(denom[idx]);
        partial += expf(-log_vars[i]) * mlpp;
    }
#pragma unroll
    for (int m = 32; m; m >>= 1) partial += __shfl_xor(partial, m, 64);
    if ((t & 63) == 0) wsum[t >> 6] = partial;
    __syncthreads();
    if (t == 0) {
        float tot = wsum[0] + wsum[1] + wsum[2] + wsum[3];
        float lvsum = 0.0f;
        for (int i = 0; i < NUM_CLASSES; ++i) lvsum += log_vars[i];
        out[0] = -(RATIO) * tot / (float)BATCH + lvsum;
    }
}

// ---------------------------------------------------------------------------
extern "C" void kernel_launch(void* const* d_in, const int* in_sizes, int n_in,
                              void* d_out, int out_size, void* d_ws, size_t ws_size,
                              hipStream_t stream)
{
    const float* preds    = (const float*)d_in[0];   // [10,2048,128] f32
    const int*   target   = (const int*)  d_in[1];   // [2048] int
    const float* log_vars = (const float*)d_in[2];   // [10] f32
    float* out = (float*)d_out;

    float* g     = (float*)d_ws;                         // 10*2048*128 f32
    float* denom = g + (size_t)NUM_CLASSES * BATCH * DIM; // 10*2048
    float* s2    = denom + (size_t)NUM_CLASSES * BATCH;   // 10*2048

    // zero the per-row accumulators (ws is poisoned to 0xAA each call)
    hipMemsetAsync(denom, 0, 2 * (size_t)NUM_CLASSES * BATCH * sizeof(float), stream);

    normalize_kernel<<<NUM_CLASSES * BATCH / 4, 256, 0, stream>>>(preds, g);
    gram_kernel<<<dim3(BATCH / BN, BATCH / BM, NUM_CLASSES), 256, 0, stream>>>(
        g, target, denom, s2);
    final_kernel<<<1, 256, 0, stream>>>(denom, s2, target, log_vars, out);
}

// Round 2
// 117.390 us; speedup vs baseline: 2.1796x; 2.1796x over previous
//
#include <hip/hip_runtime.h>
#include <hip/hip_bf16.h>
#include <math.h>

#define NUM_CLASSES 10
#define BATCH 2048
#define DIM 128
#define INV_T 14.285714285714286f   // 1/0.07; TEMPERATURE/BASE_TEMPERATURE = 1

typedef __attribute__((ext_vector_type(8))) short bf16x8;   // 8 bf16 = 4 VGPRs
typedef __attribute__((ext_vector_type(4))) float f32x4;    // MFMA accumulator

// LDS tile: 128 rows x 72 bf16 (64 data + 8 pad) = 144 B/row (16B aligned,
// row-to-row bank offset = 36 dwords = +4 banks -> 2-way aliasing = free)
#define LROW 72

// ---------------------------------------------------------------------------
// 1) Row-normalize preds -> bf16 g; also zero the denom/s2 accumulators
//    (ws is re-poisoned to 0xAA before every timed call).
// ---------------------------------------------------------------------------
__global__ __launch_bounds__(256) void normalize_kernel(
    const float* __restrict__ preds, __hip_bfloat16* __restrict__ g,
    float* __restrict__ zero_buf)
{
    int b = blockIdx.x;
    int t = threadIdx.x;
    if (t < 8) zero_buf[b * 8 + t] = 0.0f;   // 5120 blocks * 8 = 40960 floats

    int row  = b * 4 + (t >> 6);             // 4 rows per block, wave per row
    int lane = t & 63;
    const float2* src = (const float2*)(preds + (size_t)row * DIM);
    float2 v = src[lane];
    float ss = v.x * v.x + v.y * v.y;
#pragma unroll
    for (int m = 32; m; m >>= 1) ss += __shfl_xor(ss, m, 64);
    float rn = 1.0f / sqrtf(ss);
    __hip_bfloat162 o;
    o.x = __float2bfloat16(v.x * rn);
    o.y = __float2bfloat16(v.y * rn);
    *(__hip_bfloat162*)(g + (size_t)row * DIM + lane * 2) = o;
}

// ---------------------------------------------------------------------------
// 2) MFMA Gram + fused contrastive epilogue.
//    Block = 128x128 tile of one class's Gram. 256 thr = 4 waves (2x2),
//    each wave 64x64 via 4x4 frags of mfma_f32_16x16x32_bf16.
// ---------------------------------------------------------------------------
__global__ __launch_bounds__(256) void gram_kernel(
    const __hip_bfloat16* __restrict__ g, const int* __restrict__ target,
    float* __restrict__ denom, float* __restrict__ s2)
{
    const int cls  = blockIdx.z;
    const int row0 = blockIdx.y * 128;
    const int col0 = blockIdx.x * 128;
    const __hip_bfloat16* gc = g + (size_t)cls * BATCH * DIM;

    __shared__ ushort As[128 * LROW];   // 18432 B
    __shared__ ushort Bs[128 * LROW];   // 18432 B

    const int t    = threadIdx.x;
    const int wid  = t >> 6;
    const int lane = t & 63;
    const int tx   = lane & 15;         // col-within-frag (C: col=lane&15)
    const int quad = lane >> 4;         // C: row=(lane>>4)*4+reg
    const int wm   = (wid >> 1) * 64;   // wave row offset
    const int wn   = (wid & 1) * 64;    // wave col offset

    f32x4 acc[4][4] = {};

    // K split into two 64-wide halves (keeps LDS at 36.9 KB)
    for (int kt = 0; kt < 2; ++kt) {
#pragma unroll
        for (int s = 0; s < 4; ++s) {   // 1024 16B chunks per tile, 4/thread
            int q = t + s * 256;
            int r = q >> 3;             // 0..127
            int c = q & 7;              // 8 chunks of 8 bf16 per row-half
            float4 va = *(const float4*)(gc + (size_t)(row0 + r) * DIM + kt * 64 + c * 8);
            float4 vb = *(const float4*)(gc + (size_t)(col0 + r) * DIM + kt * 64 + c * 8);
            *(float4*)(&As[r * LROW + c * 8]) = va;
            *(float4*)(&Bs[r * LROW + c * 8]) = vb;
        }
        __syncthreads();

#pragma unroll
        for (int ks = 0; ks < 2; ++ks) {
            bf16x8 af[4], bg[4];
#pragma unroll
            for (int i = 0; i < 4; ++i) {
                af[i] = *(bf16x8*)(&As[(wm + i * 16 + tx) * LROW + ks * 32 + quad * 8]);
                bg[i] = *(bf16x8*)(&Bs[(wn + i * 16 + tx) * LROW + ks * 32 + quad * 8]);
            }
#pragma unroll
            for (int i = 0; i < 4; ++i)
#pragma unroll
                for (int j = 0; j < 4; ++j)
                    acc[i][j] = __builtin_amdgcn_mfma_f32_16x16x32_bf16(
                        af[i], bg[j], acc[i][j], 0, 0, 0);
        }
        __syncthreads();
    }

    // ---- epilogue: per-row sum(exp(logit)) (diag excluded) and masked
    //      sum(logit); combine across waves in LDS, then global atomics ----
    float* rowacc = (float*)As;         // reuse: 128 den + 128 sp
    rowacc[t] = 0.0f;
    __syncthreads();

    int lb[4];
#pragma unroll
    for (int j = 0; j < 4; ++j) lb[j] = (target[col0 + wn + j * 16 + tx] == cls);

#pragma unroll
    for (int i = 0; i < 4; ++i) {
#pragma unroll
        for (int r = 0; r < 4; ++r) {
            int row_loc = wm + i * 16 + quad * 4 + r;
            int rg = row0 + row_loc;
            int la = (target[rg] == cls);
            float den = 0.0f, sp = 0.0f;
#pragma unroll
            for (int j = 0; j < 4; ++j) {
                int cg = col0 + wn + j * 16 + tx;
                if (cg != rg) {
                    float logit = acc[i][j][r] * INV_T;
                    den += __expf(logit);
                    if (la == lb[j]) sp += logit;
                }
            }
#pragma unroll
            for (int m = 1; m < 16; m <<= 1) {   // reduce the 16 tx lanes
                den += __shfl_xor(den, m, 64);
                sp  += __shfl_xor(sp,  m, 64);
            }
            if (tx == 0) {
                atomicAdd(&rowacc[row_loc], den);
                atomicAdd(&rowacc[128 + row_loc], sp);
            }
        }
    }
    __syncthreads();
    if (t < 128) atomicAdd(&denom[cls * BATCH + row0 + t], rowacc[t]);
    else         atomicAdd(&s2[cls * BATCH + row0 + (t - 128)], rowacc[t]);
}

// ---------------------------------------------------------------------------
// 3) Finalize (single block, 1024 threads).
// ---------------------------------------------------------------------------
__global__ __launch_bounds__(1024) void final_kernel(
    const float* __restrict__ denom, const float* __restrict__ s2,
    const int* __restrict__ target, const float* __restrict__ log_vars,
    float* __restrict__ out)
{
    __shared__ int counts[NUM_CLASSES];
    __shared__ float wsum[16];
    int t = threadIdx.x;
    if (t < NUM_CLASSES) counts[t] = 0;
    __syncthreads();
    for (int i = t; i < BATCH; i += 1024) atomicAdd(&counts[target[i]], 1);
    __syncthreads();

    float partial = 0.0f;
    for (int idx = t; idx < NUM_CLASSES * BATCH; idx += 1024) {
        int i = idx >> 11;
        int a = idx & (BATCH - 1);
        int cnt = (target[a] == i) ? (counts[i] - 1) : (BATCH - counts[i] - 1);
        float mlpp = s2[idx] / (float)cnt - logf(denom[idx]);
        partial += __expf(-log_vars[i]) * mlpp;
    }
#pragma unroll
    for (int m = 32; m; m >>= 1) partial += __shfl_xor(partial, m, 64);
    if ((t & 63) == 0) wsum[t >> 6] = partial;
    __syncthreads();
    if (t == 0) {
        float tot = 0.0f;
        for (int w = 0; w < 16; ++w) tot += wsum[w];
        float lvsum = 0.0f;
        for (int i = 0; i < NUM_CLASSES; ++i) lvsum += log_vars[i];
        out[0] = -tot / (float)BATCH + lvsum;
    }
}

// ---------------------------------------------------------------------------
extern "C" void kernel_launch(void* const* d_in, const int* in_sizes, int n_in,
                              void* d_out, int out_size, void* d_ws, size_t ws_size,
                              hipStream_t stream)
{
    const float* preds    = (const float*)d_in[0];   // [10,2048,128] f32
    const int*   target   = (const int*)  d_in[1];   // [2048]
    const float* log_vars = (const float*)d_in[2];   // [10]
    float* out = (float*)d_out;

    __hip_bfloat16* gbf = (__hip_bfloat16*)d_ws;              // 10*2048*128 bf16
    float* denom = (float*)((char*)d_ws + (size_t)NUM_CLASSES * BATCH * DIM * 2);
    float* s2    = denom + (size_t)NUM_CLASSES * BATCH;

    normalize_kernel<<<NUM_CLASSES * BATCH / 4, 256, 0, stream>>>(preds, gbf, denom);
    gram_kernel<<<dim3(BATCH / 128, BATCH / 128, NUM_CLASSES), 256, 0, stream>>>(
        gbf, target, denom, s2);
    final_kernel<<<1, 1024, 0, stream>>>(denom, s2, target, log_vars, out);
}

// Round 3
// 99.105 us; speedup vs baseline: 2.5817x; 1.1845x over previous
//
#include <hip/hip_runtime.h>
#include <hip/hip_bf16.h>
#include <math.h>

#define NUM_CLASSES 10
#define BATCH 2048
#define DIM 128
#define INV_T 14.285714285714286f   // 1/0.07; TEMPERATURE/BASE_TEMPERATURE = 1
#define NTILE 16                    // 2048/128 stripes
#define NPAIR 136                   // NTILE*(NTILE+1)/2 upper-tri blocks
#define LROW 72                     // LDS tile leading dim (64 data + 8 pad bf16)

typedef __attribute__((ext_vector_type(8))) short bf16x8;   // 8 bf16 = 4 VGPRs
typedef __attribute__((ext_vector_type(4))) float f32x4;    // MFMA accumulator

// ---------------------------------------------------------------------------
// 1) Row-normalize preds -> bf16 g; also zero denom/s2 accumulators.
// ---------------------------------------------------------------------------
__global__ __launch_bounds__(256) void normalize_kernel(
    const float* __restrict__ preds, __hip_bfloat16* __restrict__ g,
    float* __restrict__ zero_buf)
{
    int b = blockIdx.x;
    int t = threadIdx.x;
    if (t < 8) zero_buf[b * 8 + t] = 0.0f;   // 5120 blocks * 8 = 40960 floats

    int row  = b * 4 + (t >> 6);
    int lane = t & 63;
    const float2* src = (const float2*)(preds + (size_t)row * DIM);
    float2 v = src[lane];
    float ss = v.x * v.x + v.y * v.y;
#pragma unroll
    for (int m = 32; m; m >>= 1) ss += __shfl_xor(ss, m, 64);
    float rn = 1.0f / sqrtf(ss);
    __hip_bfloat162 o;
    o.x = __float2bfloat16(v.x * rn);
    o.y = __float2bfloat16(v.y * rn);
    *(__hip_bfloat162*)(g + (size_t)row * DIM + lane * 2) = o;
}

// ---------------------------------------------------------------------------
// 2) MFMA Gram, upper-triangular blocks only (Gram is symmetric).
//    Off-diagonal blocks contribute row sums AND col sums.
//    Epilogue: register partials -> one LDS transpose -> atomics.
// ---------------------------------------------------------------------------
__global__ __launch_bounds__(256) void gram_kernel(
    const __hip_bfloat16* __restrict__ g, const int* __restrict__ target,
    float* __restrict__ denom, float* __restrict__ s2)
{
    // decode upper-tri pair (by <= bx)
    int p = blockIdx.x;
    int by = 0, rem = NTILE;
    while (p >= rem) { p -= rem; --rem; ++by; }
    const int bx   = by + p;
    const int cls  = blockIdx.y;
    const int row0 = by * 128;
    const int col0 = bx * 128;
    const bool isDiag = (by == bx);
    const __hip_bfloat16* gc = g + (size_t)cls * BATCH * DIM;

    __shared__ __align__(16) ushort smem[2 * 128 * LROW];   // 36864 B
    ushort* As = smem;
    ushort* Bs = smem + 128 * LROW;

    const int t    = threadIdx.x;
    const int wid  = t >> 6;
    const int lane = t & 63;
    const int tx   = lane & 15;         // C: col = lane&15
    const int quad = lane >> 4;         // C: row = quad*4 + reg
    const int wm   = (wid >> 1) * 64;
    const int wn   = (wid & 1) * 64;

    f32x4 acc[4][4] = {};

    for (int kt = 0; kt < 2; ++kt) {
#pragma unroll
        for (int s = 0; s < 4; ++s) {
            int q = t + s * 256;
            int r = q >> 3;             // 0..127
            int c = q & 7;
            float4 va = *(const float4*)(gc + (size_t)(row0 + r) * DIM + kt * 64 + c * 8);
            *(float4*)(&As[r * LROW + c * 8]) = va;
            if (!isDiag) {
                float4 vb = *(const float4*)(gc + (size_t)(col0 + r) * DIM + kt * 64 + c * 8);
                *(float4*)(&Bs[r * LROW + c * 8]) = vb;
            }
        }
        __syncthreads();

        const ushort* BsR = isDiag ? As : Bs;
#pragma unroll
        for (int ks = 0; ks < 2; ++ks) {
            bf16x8 af[4], bg[4];
#pragma unroll
            for (int i = 0; i < 4; ++i) {
                af[i] = *(const bf16x8*)(&As [(wm + i * 16 + tx) * LROW + ks * 32 + quad * 8]);
                bg[i] = *(const bf16x8*)(&BsR[(wn + i * 16 + tx) * LROW + ks * 32 + quad * 8]);
            }
#pragma unroll
            for (int i = 0; i < 4; ++i)
#pragma unroll
                for (int j = 0; j < 4; ++j)
                    acc[i][j] = __builtin_amdgcn_mfma_f32_16x16x32_bf16(
                        af[i], bg[j], acc[i][j], 0, 0, 0);
        }
        __syncthreads();   // also guarantees LDS is free for epilogue reuse
    }

    // ---- epilogue ----
    // labels
    unsigned laMask = 0;
#pragma unroll
    for (int i = 0; i < 4; ++i)
#pragma unroll
        for (int r = 0; r < 4; ++r)
            if (target[row0 + wm + i * 16 + quad * 4 + r] == cls)
                laMask |= 1u << (i * 4 + r);
    int lb[4];
#pragma unroll
    for (int j = 0; j < 4; ++j) lb[j] = (target[col0 + wn + j * 16 + tx] == cls);

    float2* rbuf = (float2*)smem;   // [wid][rloc(64) stride 17][tx] : 34816 B
    float2 pcol[4] = {};

#pragma unroll
    for (int i = 0; i < 4; ++i) {
        float2 prow[4] = {};
#pragma unroll
        for (int j = 0; j < 4; ++j) {
            int cg = col0 + wn + j * 16 + tx;
            int lbj = lb[j];
#pragma unroll
            for (int r = 0; r < 4; ++r) {
                int rg = row0 + wm + i * 16 + quad * 4 + r;
                float logit = acc[i][j][r] * INV_T;
                float e = __expf(logit);
                bool dg = isDiag && (cg == rg);
                e = dg ? 0.0f : e;
                bool same = (((laMask >> (i * 4 + r)) & 1) == (unsigned)lbj) && !dg;
                float sl = same ? logit : 0.0f;
                prow[r].x += e; prow[r].y += sl;
                pcol[j].x += e; pcol[j].y += sl;
            }
        }
#pragma unroll
        for (int r = 0; r < 4; ++r)
            rbuf[wid * 1088 + (i * 16 + quad * 4 + r) * 17 + tx] = prow[r];
    }
    __syncthreads();

    // row reduce: thread t<128 handles global row row0+t
    if (t < 128) {
        int rl = t & 63, grp = t >> 6;          // grp0: wids 0,1; grp1: wids 2,3
        float den = 0.0f, sp = 0.0f;
#pragma unroll
        for (int w = 0; w < 2; ++w) {
            int base = (2 * grp + w) * 1088 + rl * 17;
#pragma unroll
            for (int x = 0; x < 16; ++x) {
                float2 v = rbuf[base + x];
                den += v.x; sp += v.y;
            }
        }
        atomicAdd(&denom[cls * BATCH + row0 + t], den);
        atomicAdd(&s2   [cls * BATCH + row0 + t], sp);
    }

    if (!isDiag) {
        __syncthreads();
        float2* cbuf = (float2*)smem;   // [wid][c(64) stride 5][quad] : 10240 B
#pragma unroll
        for (int j = 0; j < 4; ++j)
            cbuf[wid * 320 + (j * 16 + tx) * 5 + quad] = pcol[j];
        __syncthreads();
        // col reduce: thread t<128 handles global row col0+t (transposed)
        if (t < 128) {
            int cl = t & 63, grp = t >> 6;      // grp0: wids 0,2; grp1: wids 1,3
            float den = 0.0f, sp = 0.0f;
#pragma unroll
            for (int w = 0; w < 2; ++w) {
                int base = (grp + 2 * w) * 320 + cl * 5;
#pragma unroll
                for (int q = 0; q < 4; ++q) {
                    float2 v = cbuf[base + q];
                    den += v.x; sp += v.y;
                }
            }
            atomicAdd(&denom[cls * BATCH + col0 + t], den);
            atomicAdd(&s2   [cls * BATCH + col0 + t], sp);
        }
    }
}

// ---------------------------------------------------------------------------
// 3) Finalize (single block, 1024 threads).
// ---------------------------------------------------------------------------
__global__ __launch_bounds__(1024) void final_kernel(
    const float* __restrict__ denom, const float* __restrict__ s2,
    const int* __restrict__ target, const float* __restrict__ log_vars,
    float* __restrict__ out)
{
    __shared__ int counts[NUM_CLASSES];
    __shared__ float wsum[16];
    int t = threadIdx.x;
    if (t < NUM_CLASSES) counts[t] = 0;
    __syncthreads();
    for (int i = t; i < BATCH; i += 1024) atomicAdd(&counts[target[i]], 1);
    __syncthreads();

    float partial = 0.0f;
    for (int idx = t; idx < NUM_CLASSES * BATCH; idx += 1024) {
        int i = idx >> 11;
        int a = idx & (BATCH - 1);
        int cnt = (target[a] == i) ? (counts[i] - 1) : (BATCH - counts[i] - 1);
        float mlpp = s2[idx] / (float)cnt - logf(denom[idx]);
        partial += __expf(-log_vars[i]) * mlpp;
    }
#pragma unroll
    for (int m = 32; m; m >>= 1) partial += __shfl_xor(partial, m, 64);
    if ((t & 63) == 0) wsum[t >> 6] = partial;
    __syncthreads();
    if (t == 0) {
        float tot = 0.0f;
        for (int w = 0; w < 16; ++w) tot += wsum[w];
        float lvsum = 0.0f;
        for (int i = 0; i < NUM_CLASSES; ++i) lvsum += log_vars[i];
        out[0] = -tot / (float)BATCH + lvsum;
    }
}

// ---------------------------------------------------------------------------
extern "C" void kernel_launch(void* const* d_in, const int* in_sizes, int n_in,
                              void* d_out, int out_size, void* d_ws, size_t ws_size,
                              hipStream_t stream)
{
    const float* preds    = (const float*)d_in[0];   // [10,2048,128] f32
    const int*   target   = (const int*)  d_in[1];   // [2048]
    const float* log_vars = (const float*)d_in[2];   // [10]
    float* out = (float*)d_out;

    __hip_bfloat16* gbf = (__hip_bfloat16*)d_ws;              // 10*2048*128 bf16
    float* denom = (float*)((char*)d_ws + (size_t)NUM_CLASSES * BATCH * DIM * 2);
    float* s2    = denom + (size_t)NUM_CLASSES * BATCH;

    normalize_kernel<<<NUM_CLASSES * BATCH / 4, 256, 0, stream>>>(preds, gbf, denom);
    gram_kernel<<<dim3(NPAIR, NUM_CLASSES), 256, 0, stream>>>(gbf, target, denom, s2);
    final_kernel<<<1, 1024, 0, stream>>>(denom, s2, target, log_vars, out);
}

// Round 4
// 91.884 us; speedup vs baseline: 2.7846x; 1.0786x over previous
//
#include <hip/hip_runtime.h>
#include <hip/hip_bf16.h>
#include <math.h>

#define NUM_CLASSES 10
#define BATCH 2048
#define DIM 128
#define INV_T 14.285714285714286f   // 1/0.07; TEMPERATURE/BASE_TEMPERATURE = 1
#define NTILE 16                    // 2048/128 row stripes
#define NPAIR 136                   // upper-triangular 128x128 block pairs

typedef __attribute__((ext_vector_type(8))) short bf16x8;   // 8 bf16 = 4 VGPRs
typedef __attribute__((ext_vector_type(4))) float f32x4;    // MFMA accumulator

// Async 16B-per-lane global->LDS. LDS dest = wave-uniform base + lane*16.
__device__ __forceinline__ void load_lds16(const void* g, void* lds) {
    __builtin_amdgcn_global_load_lds(
        (const __attribute__((address_space(1))) unsigned int*)g,
        (__attribute__((address_space(3))) unsigned int*)lds,
        16, 0, 0);
}

// ---------------------------------------------------------------------------
// 1) Row-normalize preds -> bf16 g; fuse zeroing of denom/s2 accumulators.
// ---------------------------------------------------------------------------
__global__ __launch_bounds__(256) void normalize_kernel(
    const float* __restrict__ preds, __hip_bfloat16* __restrict__ g,
    float* __restrict__ zero_buf)
{
    int b = blockIdx.x;
    int t = threadIdx.x;
    if (t < 8) zero_buf[b * 8 + t] = 0.0f;   // 5120 blocks * 8 = 40960 floats

    int row  = b * 4 + (t >> 6);
    int lane = t & 63;
    const float2* src = (const float2*)(preds + (size_t)row * DIM);
    float2 v = src[lane];
    float ss = v.x * v.x + v.y * v.y;
#pragma unroll
    for (int m = 32; m; m >>= 1) ss += __shfl_xor(ss, m, 64);
    float rn = 1.0f / sqrtf(ss);
    __hip_bfloat162 o;
    o.x = __float2bfloat16(v.x * rn);
    o.y = __float2bfloat16(v.y * rn);
    *(__hip_bfloat162*)(g + (size_t)row * DIM + lane * 2) = o;
}

// ---------------------------------------------------------------------------
// 2) MFMA Gram, upper-tri blocks only. Full-K (128) staged once via async
//    global_load_lds with XOR-swizzled layout: chunk c (16B) of row r lives
//    at position c ^ (r&15). One barrier before compute, merged epilogue.
// ---------------------------------------------------------------------------
__global__ __launch_bounds__(256) void gram_kernel(
    const __hip_bfloat16* __restrict__ g, const int* __restrict__ target,
    float* __restrict__ denom, float* __restrict__ s2)
{
    // decode upper-tri pair (by <= bx)
    int p = blockIdx.x;
    int by = 0, rem = NTILE;
    while (p >= rem) { p -= rem; --rem; ++by; }
    const int bx   = by + p;
    const int cls  = blockIdx.y;
    const int row0 = by * 128;
    const int col0 = bx * 128;
    const bool isDiag = (by == bx);
    const ushort* gc = (const ushort*)g + (size_t)cls * BATCH * DIM;

    __shared__ __align__(16) ushort smem[2 * 128 * 128];   // 64 KiB
    ushort* As = smem;
    ushort* Bs = smem + 128 * 128;

    const int t    = threadIdx.x;
    const int wid  = t >> 6;
    const int lane = t & 63;
    const int tx   = lane & 15;         // C/D: col = lane&15 ; also frag row sel
    const int quad = lane >> 4;         // C/D: row = quad*4 + reg
    const int wm   = (wid >> 1) * 64;
    const int wn   = (wid & 1) * 64;

    // ---- async staging: 8 (+8) global_load_lds_dwordx4 per thread ----
    // wave-instr s covers rows s*16+wid*4 .. +3, 16 chunks each (swizzled)
    const int lr = lane >> 4;           // row-within-4
    const int lp = lane & 15;           // chunk position 0..15
#pragma unroll
    for (int s = 0; s < 8; ++s) {
        int rb = s * 16 + wid * 4;      // wave-uniform row base
        int r  = rb + lr;
        int c  = lp ^ (r & 15);         // fetch chunk c into position lp
        load_lds16(gc + (size_t)(row0 + r) * DIM + c * 8, &As[rb * 128]);
        if (!isDiag)
            load_lds16(gc + (size_t)(col0 + r) * DIM + c * 8, &Bs[rb * 128]);
    }
    __syncthreads();   // drains vmcnt (global_load_lds) before LDS reads

    // ---- MFMA main loop: K=128 in 4 slices of 32 ----
    const ushort* BsR = isDiag ? As : Bs;
    f32x4 acc[4][4] = {};
#pragma unroll
    for (int ks = 0; ks < 4; ++ks) {
        bf16x8 af[4], bg[4];
#pragma unroll
        for (int i = 0; i < 4; ++i) {
            int pa = ((ks * 4 + quad) ^ tx) * 8;   // swizzled chunk offset
            af[i] = *(const bf16x8*)&As [(wm + i * 16 + tx) * 128 + pa];
            bg[i] = *(const bf16x8*)&BsR[(wn + i * 16 + tx) * 128 + pa];
        }
#pragma unroll
        for (int i = 0; i < 4; ++i)
#pragma unroll
            for (int j = 0; j < 4; ++j)
                acc[i][j] = __builtin_amdgcn_mfma_f32_16x16x32_bf16(
                    af[i], bg[j], acc[i][j], 0, 0, 0);
    }
    __syncthreads();   // all LDS tile reads done; safe to overwrite

    // ---- epilogue: register partials -> LDS transpose -> atomics ----
    unsigned laMask = 0;
#pragma unroll
    for (int i = 0; i < 4; ++i)
#pragma unroll
        for (int r = 0; r < 4; ++r)
            if (target[row0 + wm + i * 16 + quad * 4 + r] == cls)
                laMask |= 1u << (i * 4 + r);
    int lb[4];
#pragma unroll
    for (int j = 0; j < 4; ++j) lb[j] = (target[col0 + wn + j * 16 + tx] == cls);

    float2* rbuf = (float2*)smem;                    // [wid][64 rows x17][tx] 34816 B
    float2* cbuf = (float2*)(smem + 17408);          // [wid][64 cols x5][quad] 10240 B
    float2 pcol[4] = {};

#pragma unroll
    for (int i = 0; i < 4; ++i) {
        float2 prow[4] = {};
#pragma unroll
        for (int j = 0; j < 4; ++j) {
            int cg = col0 + wn + j * 16 + tx;
            int lbj = lb[j];
#pragma unroll
            for (int r = 0; r < 4; ++r) {
                int rg = row0 + wm + i * 16 + quad * 4 + r;
                float logit = acc[i][j][r] * INV_T;
                float e = __expf(logit);
                bool dg = isDiag && (cg == rg);
                e = dg ? 0.0f : e;
                bool same = (((laMask >> (i * 4 + r)) & 1) == (unsigned)lbj) && !dg;
                float sl = same ? logit : 0.0f;
                prow[r].x += e; prow[r].y += sl;
                pcol[j].x += e; pcol[j].y += sl;
            }
        }
#pragma unroll
        for (int r = 0; r < 4; ++r)
            rbuf[wid * 1088 + (i * 16 + quad * 4 + r) * 17 + tx] = prow[r];
    }
#pragma unroll
    for (int j = 0; j < 4; ++j)
        cbuf[wid * 320 + (j * 16 + tx) * 5 + quad] = pcol[j];
    __syncthreads();

    if (t < 128) {
        // rows: global row = row0 + t  (wids 2*grp, 2*grp+1 share wm = 64*grp)
        int rl = t & 63, grp = t >> 6;
        float den = 0.0f, sp = 0.0f;
#pragma unroll
        for (int w = 0; w < 2; ++w) {
            int base = (2 * grp + w) * 1088 + rl * 17;
#pragma unroll
            for (int x = 0; x < 16; ++x) {
                float2 v = rbuf[base + x];
                den += v.x; sp += v.y;
            }
        }
        atomicAdd(&denom[cls * BATCH + row0 + t], den);
        atomicAdd(&s2   [cls * BATCH + row0 + t], sp);
    } else if (!isDiag) {
        // cols: global row = col0 + u  (wids grp, grp+2 share wn = 64*grp)
        int u = t - 128;
        int cl = u & 63, grp = u >> 6;
        float den = 0.0f, sp = 0.0f;
#pragma unroll
        for (int w = 0; w < 2; ++w) {
            int base = (grp + 2 * w) * 320 + cl * 5;
#pragma unroll
            for (int q = 0; q < 4; ++q) {
                float2 v = cbuf[base + q];
                den += v.x; sp += v.y;
            }
        }
        atomicAdd(&denom[cls * BATCH + col0 + u], den);
        atomicAdd(&s2   [cls * BATCH + col0 + u], sp);
    }
}

// ---------------------------------------------------------------------------
// 3) Finalize (single block, 1024 threads).
// ---------------------------------------------------------------------------
__global__ __launch_bounds__(1024) void final_kernel(
    const float* __restrict__ denom, const float* __restrict__ s2,
    const int* __restrict__ target, const float* __restrict__ log_vars,
    float* __restrict__ out)
{
    __shared__ int counts[NUM_CLASSES];
    __shared__ float wsum[16];
    int t = threadIdx.x;
    if (t < NUM_CLASSES) counts[t] = 0;
    __syncthreads();
    for (int i = t; i < BATCH; i += 1024) atomicAdd(&counts[target[i]], 1);
    __syncthreads();

    float partial = 0.0f;
    for (int idx = t; idx < NUM_CLASSES * BATCH; idx += 1024) {
        int i = idx >> 11;
        int a = idx & (BATCH - 1);
        int cnt = (target[a] == i) ? (counts[i] - 1) : (BATCH - counts[i] - 1);
        float mlpp = s2[idx] / (float)cnt - logf(denom[idx]);
        partial += __expf(-log_vars[i]) * mlpp;
    }
#pragma unroll
    for (int m = 32; m; m >>= 1) partial += __shfl_xor(partial, m, 64);
    if ((t & 63) == 0) wsum[t >> 6] = partial;
    __syncthreads();
    if (t == 0) {
        float tot = 0.0f;
        for (int w = 0; w < 16; ++w) tot += wsum[w];
        float lvsum = 0.0f;
        for (int i = 0; i < NUM_CLASSES; ++i) lvsum += log_vars[i];
        out[0] = -tot / (float)BATCH + lvsum;
    }
}

// ---------------------------------------------------------------------------
extern "C" void kernel_launch(void* const* d_in, const int* in_sizes, int n_in,
                              void* d_out, int out_size, void* d_ws, size_t ws_size,
                              hipStream_t stream)
{
    const float* preds    = (const float*)d_in[0];   // [10,2048,128] f32
    const int*   target   = (const int*)  d_in[1];   // [2048]
    const float* log_vars = (const float*)d_in[2];   // [10]
    float* out = (float*)d_out;

    __hip_bfloat16* gbf = (__hip_bfloat16*)d_ws;              // 10*2048*128 bf16
    float* denom = (float*)((char*)d_ws + (size_t)NUM_CLASSES * BATCH * DIM * 2);
    float* s2    = denom + (size_t)NUM_CLASSES * BATCH;

    normalize_kernel<<<NUM_CLASSES * BATCH / 4, 256, 0, stream>>>(preds, gbf, denom);
    gram_kernel<<<dim3(NPAIR, NUM_CLASSES), 256, 0, stream>>>(gbf, target, denom, s2);
    final_kernel<<<1, 1024, 0, stream>>>(denom, s2, target, log_vars, out);
}